// Round 1
// 249.994 us; speedup vs baseline: 1.1155x; 1.1155x over previous
//
#include <hip/hip_runtime.h>
#include <hip/hip_bf16.h>

#define N_NODES 50000
#define N_EDGES 800000
#define IN_F 256
#define HEADS 8
#define OUT_F 32
#define HF (HEADS * OUT_F)   // 256
#define SLOPE 0.2f

typedef __attribute__((ext_vector_type(8))) short bf16x8;
typedef __attribute__((ext_vector_type(4))) float f32x4;

__device__ __forceinline__ ushort f2bf(float f) {
  union { float f; unsigned u; } x;
  x.f = f;
  unsigned r = x.u + 0x7FFFu + ((x.u >> 16) & 1u);  // RNE
  return (ushort)(r >> 16);
}

__device__ __forceinline__ float bf2f_lo(unsigned u) {
  return __uint_as_float(u << 16);
}
__device__ __forceinline__ float bf2f_hi(unsigned u) {
  return __uint_as_float(u & 0xFFFF0000u);
}

// ---------------------------------------------------------------------------
// Kernel 0: Bt[n][k] = bf16(fc_w[k][n])  (256x256 transpose+convert, one-time)
// ---------------------------------------------------------------------------
__global__ void wt_kernel(const float* __restrict__ fc_w,
                          ushort* __restrict__ Bt) {
  __shared__ float tile[32][33];
  const int bx = blockIdx.x * 32;  // n block
  const int by = blockIdx.y * 32;  // k block
  const int tx = threadIdx.x;      // 0..31
  const int ty = threadIdx.y;      // 0..7
#pragma unroll
  for (int i = 0; i < 32; i += 8)
    tile[ty + i][tx] = fc_w[(size_t)(by + ty + i) * HF + bx + tx];
  __syncthreads();
#pragma unroll
  for (int i = 0; i < 32; i += 8)
    Bt[(size_t)(bx + ty + i) * IN_F + by + tx] = f2bf(tile[tx][ty + i]);
}

// ---------------------------------------------------------------------------
// Kernel 1: bf16 MFMA GEMM  Cb[M,256](bf16) = A[M,256](f32) @ B[256,256]
// BM=64 x BN=256 tile, BK=32, 256 threads = 4 waves. Wave w owns cols w*64.
// Each wave: 4x4 frags of 16x16x32 -> 16 MFMA per K-step. B comes from the
// pre-transposed bf16 Bt[n][k] so staging is pure 16B vector copies.
// A rows are read exactly once (BN spans the full output width).
// ---------------------------------------------------------------------------
#define BM 64
#define BN 256
#define BK 32
#define LDA 40   // padded LDS row stride (bf16 elems): 80 B, 16B-aligned

__global__ __launch_bounds__(256) void gemm_mfma(
    const float* __restrict__ A, const ushort* __restrict__ Bt,
    ushort* __restrict__ Cb, int M) {
  __shared__ __align__(16) ushort As[BM * LDA];   // [m][k]  5 KB
  __shared__ __align__(16) ushort Bs[BN * LDA];   // [n][k] 20 KB

  const int t = threadIdx.x;
  const int wave = t >> 6;
  const int lane = t & 63;
  const int m0 = blockIdx.x * BM;

  // staging indices
  const int ar = t >> 2;         // A row 0..63
  const int ak = (t & 3) * 8;    // A k-offset {0,8,16,24}
  const int br = t >> 2;         // B base n-row 0..63 (+i*64)
  const int bk = (t & 3) * 8;    // B k-offset {0,8,16,24}

  // compute indices
  const int q = lane >> 4;       // quad 0..3
  const int l16 = lane & 15;
  const int wn = wave * 64;      // wave's column base

  f32x4 acc[4][4] = {};

  for (int k0 = 0; k0 < IN_F; k0 += BK) {
    // --- stage A tile (64 x 32 f32 -> bf16)
    {
      float4 v0 = make_float4(0.f, 0.f, 0.f, 0.f);
      float4 v1 = make_float4(0.f, 0.f, 0.f, 0.f);
      if (m0 + ar < M) {
        const float* ap = &A[(size_t)(m0 + ar) * IN_F + k0 + ak];
        v0 = *(const float4*)ap;
        v1 = *(const float4*)(ap + 4);
      }
      union { ushort s[8]; uint4 v; } u;
      u.s[0] = f2bf(v0.x); u.s[1] = f2bf(v0.y);
      u.s[2] = f2bf(v0.z); u.s[3] = f2bf(v0.w);
      u.s[4] = f2bf(v1.x); u.s[5] = f2bf(v1.y);
      u.s[6] = f2bf(v1.z); u.s[7] = f2bf(v1.w);
      *(uint4*)&As[ar * LDA + ak] = u.v;
    }
    // --- stage B tile (256 n-rows x 32 k) from bf16 Bt, 16B copies
#pragma unroll
    for (int i = 0; i < 4; ++i) {
      const int n = br + i * 64;
      *(uint4*)&Bs[n * LDA + bk] =
          *(const uint4*)&Bt[(size_t)n * IN_F + k0 + bk];
    }
    __syncthreads();

    bf16x8 aF[4], bF[4];
#pragma unroll
    for (int i = 0; i < 4; ++i)
      aF[i] = *(const bf16x8*)&As[(i * 16 + l16) * LDA + q * 8];
#pragma unroll
    for (int jj = 0; jj < 4; ++jj)
      bF[jj] = *(const bf16x8*)&Bs[(wn + jj * 16 + l16) * LDA + q * 8];
#pragma unroll
    for (int i = 0; i < 4; ++i)
#pragma unroll
      for (int jj = 0; jj < 4; ++jj)
        acc[i][jj] = __builtin_amdgcn_mfma_f32_16x16x32_bf16(
            aF[i], bF[jj], acc[i][jj], 0, 0, 0);
    __syncthreads();
  }

  // --- epilogue: C/D layout col=l16, row=q*4+reg; store bf16
#pragma unroll
  for (int i = 0; i < 4; ++i) {
#pragma unroll
    for (int r = 0; r < 4; ++r) {
      const int row = m0 + 16 * i + q * 4 + r;
      if (row < M) {
#pragma unroll
        for (int jj = 0; jj < 4; ++jj) {
          const int col = wn + 16 * jj + l16;
          Cb[(size_t)row * HF + col] = f2bf(acc[i][jj][r]);
        }
      }
    }
  }
}

// ---------------------------------------------------------------------------
// Kernel 2: wl[k,h] = sum_f fc_w[k, h*32+f] * attn_l[h,f]
// ---------------------------------------------------------------------------
__global__ void wl_kernel(const float* __restrict__ fc_w,
                          const float* __restrict__ attn_l,
                          float* __restrict__ wl) {
  const int idx = blockIdx.x * blockDim.x + threadIdx.x;  // 0..2047
  const int k = idx >> 3;
  const int h = idx & 7;
  const float* fp = &fc_w[(size_t)k * HF + h * OUT_F];
  const float* ap = &attn_l[h * OUT_F];
  float acc = 0.f;
#pragma unroll
  for (int f = 0; f < OUT_F; f += 4) {
    float4 a = *(const float4*)&fp[f];
    float4 b = *(const float4*)&ap[f];
    acc += a.x * b.x + a.y * b.y + a.z * b.z + a.w * b.w;
  }
  wl[idx] = acc;
}

// ---------------------------------------------------------------------------
// Kernel 3: el[n,h] = sum_k feat[n,k] * wl[k,h]
// ---------------------------------------------------------------------------
__global__ __launch_bounds__(256) void el_kernel(
    const float* __restrict__ feat, const float* __restrict__ wl,
    float* __restrict__ el, int NH) {
  __shared__ float wls[IN_F * HEADS];  // 8 KB
  const int t = threadIdx.x;
#pragma unroll
  for (int i = 0; i < (IN_F * HEADS) / 256; ++i)
    wls[i * 256 + t] = wl[i * 256 + t];
  __syncthreads();

  const int idx = blockIdx.x * 256 + t;
  if (idx >= NH) return;
  const int n = idx >> 3;
  const int h = idx & 7;
  const float* fp = &feat[(size_t)n * IN_F];
  float acc = 0.f;
#pragma unroll 8
  for (int k0 = 0; k0 < IN_F; k0 += 4) {
    float4 v = *(const float4*)&fp[k0];
    acc += v.x * wls[(k0 + 0) * 8 + h] + v.y * wls[(k0 + 1) * 8 + h] +
           v.z * wls[(k0 + 2) * 8 + h] + v.w * wls[(k0 + 3) * 8 + h];
  }
  el[idx] = acc;
}

// ---------------------------------------------------------------------------
// Kernel 4: CSR row_ptr from sorted dst via binary search
// ---------------------------------------------------------------------------
__global__ void rowptr_kernel(const int* __restrict__ dst,
                              int* __restrict__ row_ptr, int N, int E) {
  int i = blockIdx.x * blockDim.x + threadIdx.x;
  if (i > N) return;
  int lo = 0, hi = E;
  while (lo < hi) {
    int mid = (lo + hi) >> 1;
    if (dst[mid] < i) lo = mid + 1; else hi = mid;
  }
  row_ptr[i] = lo;
}

// ---------------------------------------------------------------------------
// Kernel 5: per-destination softmax + weighted aggregation.
// One block (256 threads) per node.
// Score phases: thread (j = t>>3 in 0..31, h8 = t&7); shuffle-tree reduces.
// Gather phase: wave r (0..3) handles edge e0+r, lane c (0..63) handles
// features 4c..4c+3 via one 8-byte bf16x4 load -> 4 independent FMA chains.
// ---------------------------------------------------------------------------
#define CHUNK 64

__global__ __launch_bounds__(256) void aggregate_kernel(
    const ushort* __restrict__ featb, const float* __restrict__ el,
    const int* __restrict__ src, const int* __restrict__ row_ptr,
    float* __restrict__ out) {
  const int v = blockIdx.x;
  const int t = threadIdx.x;
  const int beg = row_ptr[v];
  const int deg = row_ptr[v + 1] - beg;

  if (deg == 0) {  // segment_sum over empty segment = 0
    out[(size_t)v * HF + t] = 0.f;
    return;
  }

  __shared__ float s_wred[4][HEADS];                 // cross-wave partials
  __shared__ __align__(16) float s_alpha[CHUNK][HEADS];
  __shared__ int s_src[CHUNK];
  __shared__ __align__(16) float s_out[4][HF];       // per-wave output partials

  const int lane = t & 63;
  const int wave = t >> 6;
  const int j = t >> 3;        // 0..31: edge slot for score phases
  const int h8 = t & 7;        // head for score phases
  const int h = lane >> 3;     // head for gather (features lane*4 .. lane*4+3)

  // Phase 1: m[h] = max over incoming edges of el[src[e], h]
  float mx = -1e30f;
  for (int e = j; e < deg; e += 32)
    mx = fmaxf(mx, el[(size_t)src[beg + e] * HEADS + h8]);
  mx = fmaxf(mx, __shfl_xor(mx, 8));
  mx = fmaxf(mx, __shfl_xor(mx, 16));
  mx = fmaxf(mx, __shfl_xor(mx, 32));
  if (lane < HEADS) s_wred[wave][lane] = mx;
  __syncthreads();
  const float m = fmaxf(fmaxf(s_wred[0][h8], s_wred[1][h8]),
                        fmaxf(s_wred[2][h8], s_wred[3][h8]));

  // Phase 2: per-chunk alpha into LDS, then 4-edge-wide vectorized gather
  float4 acc = make_float4(0.f, 0.f, 0.f, 0.f);
  float ssum = 0.f;

  for (int c0 = 0; c0 < deg; c0 += CHUNK) {
    const int cn = min(CHUNK, deg - c0);
    const int cnp = (cn + 3) & ~3;   // pad to multiple of 4 edges
    __syncthreads();  // protect s_alpha/s_src from previous iteration readers
    for (int cc = j; cc < cnp; cc += 32) {
      if (cc < cn) {
        const int s = src[beg + c0 + cc];
        if (h8 == 0) s_src[cc] = s;
        const float z = el[(size_t)s * HEADS + h8] - m;
        const float w = (z >= 0.f) ? z : SLOPE * z;
        const float cf = __expf(w);
        s_alpha[cc][h8] = cf;
        ssum += cf;
      } else {  // pad edges: zero weight, safe source index
        if (h8 == 0) s_src[cc] = 0;
        s_alpha[cc][h8] = 0.f;
      }
    }
    __syncthreads();
#pragma unroll 2
    for (int e0 = 0; e0 < cnp; e0 += 4) {
      const int e = e0 + wave;
      const int s = s_src[e];
      const float a = s_alpha[e][h];
      const uint2 u = *(const uint2*)&featb[(size_t)s * HF + lane * 4];
      acc.x = fmaf(a, bf2f_lo(u.x), acc.x);
      acc.y = fmaf(a, bf2f_hi(u.x), acc.y);
      acc.z = fmaf(a, bf2f_lo(u.y), acc.z);
      acc.w = fmaf(a, bf2f_hi(u.y), acc.w);
    }
  }

  // Reduce coeff sums over j (shuffle tree + cross-wave), outputs over waves
  ssum += __shfl_xor(ssum, 8);
  ssum += __shfl_xor(ssum, 16);
  ssum += __shfl_xor(ssum, 32);
  if (lane < HEADS) s_wred[wave][lane] = ssum;   // safe: all m-reads precede
  *(float4*)&s_out[wave][lane * 4] = acc;        // the chunk-loop barriers
  __syncthreads();

  const int ho = t >> 5;  // head owned for output element t
  const float ssum_all =
      s_wred[0][ho] + s_wred[1][ho] + s_wred[2][ho] + s_wred[3][ho];
  const float r = s_out[0][t] + s_out[1][t] + s_out[2][t] + s_out[3][t];
  out[(size_t)v * HF + t] = r / ssum_all;
}

// ---------------------------------------------------------------------------
extern "C" void kernel_launch(void* const* d_in, const int* in_sizes, int n_in,
                              void* d_out, int out_size, void* d_ws,
                              size_t ws_size, hipStream_t stream) {
  const float* feat = (const float*)d_in[0];
  const float* fc_w = (const float*)d_in[1];
  const float* attn_l = (const float*)d_in[2];
  // d_in[3] = attn_r: unused — cancels exactly in the edge softmax.
  const int* src = (const int*)d_in[4];
  const int* dst = (const int*)d_in[5];
  float* out = (float*)d_out;

  const int N = N_NODES;
  const int E = N_EDGES;

  // workspace layout (16B-aligned sections)
  ushort* featb = (ushort*)d_ws;                       // N*256 bf16 (25.6 MB)
  float* el = (float*)(featb + (size_t)N * HF);        // N*8 f32
  float* wl = el + (size_t)N * HEADS;                  // 256*8 f32
  ushort* Bt = (ushort*)(wl + IN_F * HEADS);           // 256*256 bf16 (128 KB)
  int* row_ptr = (int*)(Bt + (size_t)IN_F * HF);       // N+1 ints

  wt_kernel<<<dim3(8, 8), dim3(32, 8), 0, stream>>>(fc_w, Bt);

  gemm_mfma<<<(N + BM - 1) / BM, 256, 0, stream>>>(feat, Bt, featb, N);

  wl_kernel<<<(IN_F * HEADS) / 256, 256, 0, stream>>>(fc_w, attn_l, wl);

  el_kernel<<<(N * HEADS + 255) / 256, 256, 0, stream>>>(feat, wl, el,
                                                         N * HEADS);

  rowptr_kernel<<<(N + 1 + 255) / 256, 256, 0, stream>>>(dst, row_ptr, N, E);

  aggregate_kernel<<<N, 256, 0, stream>>>(featb, el, src, row_ptr, out);
}